// Round 4
// baseline (2967.134 us; speedup 1.0000x reference)
//
#include <hip/hip_runtime.h>
#include <stdint.h>

#define LSEQ 1024
#define HDIM 1024
#define DDIM 2048
#define BL 2048
#define NST 16
#define LC 256          // chunk length in tokens
#define XROWS (LC + 3)  // chunk rows + 3-row conv halo

static __device__ __forceinline__ float silu_f(float v) { return v / (1.f + __expf(-v)); }

// ---------------- K0: per-row rmsnorm scale ----------------
__global__ __launch_bounds__(256) void k_rowscale(const float* __restrict__ inp,
                                                  float* __restrict__ rs) {
  int row = blockIdx.x;
  int t = threadIdx.x;
  float4 xv = *(const float4*)(inp + (size_t)row * HDIM + t * 4);
  float ss = xv.x * xv.x + xv.y * xv.y + xv.z * xv.z + xv.w * xv.w;
  for (int off = 32; off > 0; off >>= 1) ss += __shfl_down(ss, off);
  __shared__ float red[4];
  if ((t & 63) == 0) red[t >> 6] = ss;
  __syncthreads();
  if (t == 0) {
    float tot = red[0] + red[1] + red[2] + red[3];
    rs[row] = rsqrtf(tot * (1.f / HDIM) + 1e-6f);
  }
}

// ---------------- halo: copy last 3 x-rows of previous chunk to rows [0,3) ----------------
__global__ __launch_bounds__(256) void k_halo(float* __restrict__ xgb) {
  int idx = blockIdx.x * 256 + threadIdx.x;  // 2 batches * 3 rows * 2048 cols = 12288
  int b = idx / (3 * DDIM);
  int rem = idx - b * 3 * DDIM;
  int r = rem / DDIM;
  int c = rem - r * DDIM;
  xgb[(size_t)(b * XROWS + r) * 4096 + c] = xgb[(size_t)(b * XROWS + LC + r) * 4096 + c];
}

// ---------------- K1: in_proj GEMM (rmsnorm fused), chunk of 2*LC rows ----------------
__global__ __launch_bounds__(256) void k_gemm1(const float* __restrict__ A,
                                               const float* __restrict__ W,
                                               const float* __restrict__ bias,
                                               const float* __restrict__ rscale,
                                               const float* __restrict__ nw,
                                               float* __restrict__ xgb, int l0) {
  __shared__ float As[16][68];
  __shared__ float Ws[16][68];
  int tid = threadIdx.x;
  int tx = tid & 15, ty = tid >> 4;
  int m0 = blockIdx.y * 64, n0 = blockIdx.x * 64;
  int lm = tid >> 2, lk = (tid & 3) * 4;
  int r = m0 + lm;                                   // 0..511 chunk row
  int gin = ((r >> 8) << 10) + l0 + (r & 255);       // global BL row
  const float* Ag = A + (size_t)gin * HDIM + lk;
  const float* Wg = W + (size_t)(n0 + lm) * HDIM + lk;
  float scale = rscale[gin];
  float c[4][4] = {};
  for (int k0 = 0; k0 < HDIM; k0 += 16) {
    float4 av = *(const float4*)(Ag + k0);
    float4 wv = *(const float4*)(Wg + k0);
    float4 nv = *(const float4*)(nw + k0 + lk);
    float a0 = av.x * scale * nv.x;
    float a1 = av.y * scale * nv.y;
    float a2 = av.z * scale * nv.z;
    float a3 = av.w * scale * nv.w;
    __syncthreads();
    As[lk + 0][lm] = a0; As[lk + 1][lm] = a1;
    As[lk + 2][lm] = a2; As[lk + 3][lm] = a3;
    Ws[lk + 0][lm] = wv.x; Ws[lk + 1][lm] = wv.y;
    Ws[lk + 2][lm] = wv.z; Ws[lk + 3][lm] = wv.w;
    __syncthreads();
#pragma unroll
    for (int kk = 0; kk < 16; kk++) {
      float4 a = *(const float4*)&As[kk][ty * 4];
      float4 w = *(const float4*)&Ws[kk][tx * 4];
      c[0][0] += a.x * w.x; c[0][1] += a.x * w.y; c[0][2] += a.x * w.z; c[0][3] += a.x * w.w;
      c[1][0] += a.y * w.x; c[1][1] += a.y * w.y; c[1][2] += a.y * w.z; c[1][3] += a.y * w.w;
      c[2][0] += a.z * w.x; c[2][1] += a.z * w.y; c[2][2] += a.z * w.z; c[2][3] += a.z * w.w;
      c[3][0] += a.w * w.x; c[3][1] += a.w * w.y; c[3][2] += a.w * w.z; c[3][3] += a.w * w.w;
    }
  }
  int col = n0 + tx * 4;
#pragma unroll
  for (int i = 0; i < 4; i++) {
    int rr = m0 + ty * 4 + i;
    int lout = (rr >> 8) * XROWS + 3 + (rr & 255);   // chunk-local xgb row
#pragma unroll
    for (int j = 0; j < 4; j++) {
      xgb[(size_t)lout * 4096 + col + j] = c[i][j] + bias[col + j];
    }
  }
}

// ---------------- K2: conv+silu (in LDS) then x_proj (96 outs/token) ----------------
__global__ __launch_bounds__(256) void k_xprojc(const float* __restrict__ xgb,
                                                const float* __restrict__ cw,
                                                const float* __restrict__ cb,
                                                const float* __restrict__ w,
                                                const float* __restrict__ b,
                                                float* __restrict__ proj, int l0) {
  __shared__ float row[DDIM];
  int bb = blockIdx.x >> 8, lc = blockIdx.x & 255;
  int gl = l0 + lc;
  int t = threadIdx.x;
  int d = t * 8;
  float acc[8];
#pragma unroll
  for (int i = 0; i < 8; i++) acc[i] = cb[d + i];
  float cwv[8][4];
#pragma unroll
  for (int i = 0; i < 8; i++) {
    float4 v = *(const float4*)(cw + (d + i) * 4);
    cwv[i][0] = v.x; cwv[i][1] = v.y; cwv[i][2] = v.z; cwv[i][3] = v.w;
  }
#pragma unroll
  for (int j = 0; j < 4; j++) {
    if (gl - 3 + j >= 0) {  // causal guard; halo rows valid when this holds
      const float* xr = xgb + (size_t)(bb * XROWS + lc + j) * 4096 + d;
      float4 v0 = *(const float4*)xr;
      float4 v1 = *(const float4*)(xr + 4);
      acc[0] += v0.x * cwv[0][j]; acc[1] += v0.y * cwv[1][j];
      acc[2] += v0.z * cwv[2][j]; acc[3] += v0.w * cwv[3][j];
      acc[4] += v1.x * cwv[4][j]; acc[5] += v1.y * cwv[5][j];
      acc[6] += v1.z * cwv[6][j]; acc[7] += v1.w * cwv[7][j];
    }
  }
#pragma unroll
  for (int i = 0; i < 8; i++) row[d + i] = silu_f(acc[i]);
  __syncthreads();
  int wv = t >> 6, lane = t & 63;
  for (int o = wv; o < 96; o += 4) {
    const float* wr = w + (size_t)o * DDIM;
    float s = 0.f;
    for (int k = lane; k < DDIM; k += 64) s += row[k] * wr[k];
    s += __shfl_xor(s, 32); s += __shfl_xor(s, 16);
    s += __shfl_xor(s, 8);  s += __shfl_xor(s, 4);
    s += __shfl_xor(s, 2);  s += __shfl_xor(s, 1);
    if (lane == 0) proj[(size_t)((bb << 10) + gl) * 96 + o] = s + b[o];
  }
}

// ---------------- K3: selective scan chunk (ref cumsum-with-clip), conv+dtproj fused ----------------
__global__ __launch_bounds__(256) void k_scan(const float* __restrict__ proj,
                                              const float* __restrict__ xgb,
                                              const float* __restrict__ cw,
                                              const float* __restrict__ cb,
                                              const float* __restrict__ dtw,
                                              const float* __restrict__ dtb,
                                              const float* __restrict__ alog,
                                              const float* __restrict__ dparam,
                                              const float* __restrict__ cs,
                                              float* __restrict__ cumA,
                                              float* __restrict__ SA,
                                              float* __restrict__ PA,
                                              float* __restrict__ yb, int l0) {
  int grp = threadIdx.x >> 4;
  int n = threadIdx.x & 15;
  int cidx = blockIdx.x * 16 + grp;   // (b,d) channel
  int b = cidx >> 11;
  int d = cidx & (DDIM - 1);
  float Aval = -__expf(alog[d * NST + n]);
  float state = cs[(size_t)(b * DDIM + d) * NST + n];
  float Dp = dparam[d];
  float4 cwv = *(const float4*)(cw + d * 4);
  float w0 = cwv.x, w1 = cwv.y, w2 = cwv.z, w3 = cwv.w;
  float cbv = cb[d];
  float4 dwv = *(const float4*)(dtw + (size_t)d * 64 + n * 4);
  float dtbv = dtb[d];
  int ci = (cidx << 4) | n;
  float cum, S, Pp, xm1, xm2, xm3;
  if (l0 == 0) {
    cum = 0.f; S = 0.f; Pp = 1.f; xm1 = 0.f; xm2 = 0.f; xm3 = 0.f;
  } else {
    cum = cumA[ci]; S = SA[ci]; Pp = PA[ci];
    xm1 = xgb[(size_t)(b * XROWS + 2) * 4096 + d];
    xm2 = xgb[(size_t)(b * XROWS + 1) * 4096 + d];
    xm3 = xgb[(size_t)(b * XROWS + 0) * 4096 + d];
  }
  const float* pr = proj + ((size_t)(b << 10) + l0) * 96;
  const float* xbase = xgb + (size_t)(b * XROWS + 3) * 4096 + d;
  float* yp = yb + (size_t)(b << 8) * DDIM + d;
  for (int lc = 0; lc < LC; lc++) {
    float xcur = xbase[(size_t)lc * 4096];
    float xc = silu_f(cbv + w3 * xcur + w2 * xm1 + w1 * xm2 + w0 * xm3);
    xm3 = xm2; xm2 = xm1; xm1 = xcur;
    float4 dtv = *(const float4*)(pr + (size_t)lc * 96 + n * 4);
    float part = dtv.x * dwv.x + dtv.y * dwv.y + dtv.z * dwv.z + dtv.w * dwv.w;
    part += __shfl_xor(part, 8);
    part += __shfl_xor(part, 4);
    part += __shfl_xor(part, 2);
    part += __shfl_xor(part, 1);
    float pre = part + dtbv;
    float dl = (pre > 20.f) ? pre : log1pf(__expf(pre));
    float Bn = pr[(size_t)lc * 96 + 64 + n];
    float Cn = pr[(size_t)lc * 96 + 80 + n];
    cum += dl * Aval;
    float P = __expf(cum);            // cumsum_deltaA[l]
    float sh = Pp;                    // shifted[l]
    S += (dl * Bn * xc) / fmaxf(sh, 1e-10f);
    float h = S * sh + state * P;
    Pp = P;
    float contrib = h * Cn;
    contrib += __shfl_xor(contrib, 8);
    contrib += __shfl_xor(contrib, 4);
    contrib += __shfl_xor(contrib, 2);
    contrib += __shfl_xor(contrib, 1);
    if (n == 0) {
      float g = xbase[(size_t)lc * 4096 + DDIM];
      yp[(size_t)lc * DDIM] = (contrib + xc * Dp) * silu_f(g);
    }
  }
  cumA[ci] = cum; SA[ci] = S; PA[ci] = Pp;
}

// ---------------- K4: out_proj GEMM + bias + residual ----------------
__global__ __launch_bounds__(256) void k_gemm2(const float* __restrict__ A,  // yb [512][2048]
                                               const float* __restrict__ W,
                                               const float* __restrict__ bias,
                                               const float* __restrict__ resid,
                                               float* __restrict__ out, int l0) {
  __shared__ float As[16][68];
  __shared__ float Ws[16][68];
  int tid = threadIdx.x;
  int tx = tid & 15, ty = tid >> 4;
  int m0 = blockIdx.y * 64, n0 = blockIdx.x * 64;
  int lm = tid >> 2, lk = (tid & 3) * 4;
  const float* Ag = A + (size_t)(m0 + lm) * DDIM + lk;
  const float* Wg = W + (size_t)(n0 + lm) * DDIM + lk;
  float c[4][4] = {};
  for (int k0 = 0; k0 < DDIM; k0 += 16) {
    float4 av = *(const float4*)(Ag + k0);
    float4 wv = *(const float4*)(Wg + k0);
    __syncthreads();
    As[lk + 0][lm] = av.x; As[lk + 1][lm] = av.y;
    As[lk + 2][lm] = av.z; As[lk + 3][lm] = av.w;
    Ws[lk + 0][lm] = wv.x; Ws[lk + 1][lm] = wv.y;
    Ws[lk + 2][lm] = wv.z; Ws[lk + 3][lm] = wv.w;
    __syncthreads();
#pragma unroll
    for (int kk = 0; kk < 16; kk++) {
      float4 a = *(const float4*)&As[kk][ty * 4];
      float4 w = *(const float4*)&Ws[kk][tx * 4];
      c[0][0] += a.x * w.x; c[0][1] += a.x * w.y; c[0][2] += a.x * w.z; c[0][3] += a.x * w.w;
      c[1][0] += a.y * w.x; c[1][1] += a.y * w.y; c[1][2] += a.y * w.z; c[1][3] += a.y * w.w;
      c[2][0] += a.z * w.x; c[2][1] += a.z * w.y; c[2][2] += a.z * w.z; c[2][3] += a.z * w.w;
      c[3][0] += a.w * w.x; c[3][1] += a.w * w.y; c[3][2] += a.w * w.z; c[3][3] += a.w * w.w;
    }
  }
  int col = n0 + tx * 4;
#pragma unroll
  for (int i = 0; i < 4; i++) {
    int rr = m0 + ty * 4 + i;
    int gout = ((rr >> 8) << 10) + l0 + (rr & 255);
#pragma unroll
    for (int j = 0; j < 4; j++) {
      out[(size_t)gout * HDIM + col + j] =
          c[i][j] + bias[col + j] + resid[(size_t)gout * HDIM + col + j];
    }
  }
}

extern "C" void kernel_launch(void* const* d_in, const int* in_sizes, int n_in,
                              void* d_out, int out_size, void* d_ws, size_t ws_size,
                              hipStream_t stream) {
  const float* inp    = (const float*)d_in[0];
  const float* cstate = (const float*)d_in[1];
  const float* norm_w = (const float*)d_in[2];
  const float* w1     = (const float*)d_in[3];
  const float* b1     = (const float*)d_in[4];
  const float* convw  = (const float*)d_in[5];
  const float* convb  = (const float*)d_in[6];
  const float* xpw    = (const float*)d_in[7];
  const float* xpb    = (const float*)d_in[8];
  const float* dtw    = (const float*)d_in[9];
  const float* dtb    = (const float*)d_in[10];
  const float* alog   = (const float*)d_in[11];
  const float* dparam = (const float*)d_in[12];
  const float* wo     = (const float*)d_in[13];
  const float* bo     = (const float*)d_in[14];
  float* out = (float*)d_out;

  // workspace layout, 14,316,544 B total
  char* wsb = (char*)d_ws;
  float* rscale = (float*)(wsb + 0);          //     8,192 B
  float* proj   = (float*)(wsb + 8192);       //   786,432 B  [2048][96]
  float* cumA   = (float*)(wsb + 794624);     //   262,144 B  [65536]
  float* SA     = (float*)(wsb + 1056768);    //   262,144 B
  float* PA     = (float*)(wsb + 1318912);    //   262,144 B
  float* xgb    = (float*)(wsb + 1581056);    // 8,486,912 B  [2][259][4096]
  float* yb     = (float*)(wsb + 10067968);   // 4,194,304 B  [2][256][2048]

  k_rowscale<<<BL, 256, 0, stream>>>(inp, rscale);
  for (int c = 0; c < 4; c++) {
    int l0 = c * LC;
    if (c > 0) k_halo<<<48, 256, 0, stream>>>(xgb);
    k_gemm1<<<dim3(64, 8), 256, 0, stream>>>(inp, w1, b1, rscale, norm_w, xgb, l0);
    k_xprojc<<<2 * LC, 256, 0, stream>>>(xgb, convw, convb, xpw, xpb, proj, l0);
    k_scan<<<(2 * DDIM) / 16, 256, 0, stream>>>(proj, xgb, convw, convb, dtw, dtb,
                                                alog, dparam, cstate, cumA, SA, PA, yb, l0);
    k_gemm2<<<dim3(16, 8), 256, 0, stream>>>(yb, wo, bo, inp, out, l0);
  }
}

// Round 5
// 1882.191 us; speedup vs baseline: 1.5764x; 1.5764x over previous
//
#include <hip/hip_runtime.h>
#include <stdint.h>

#define LSEQ 1024
#define HDIM 1024
#define DDIM 2048
#define BL 2048
#define NST 16
#define LC 256          // chunk length in tokens
#define XROWS (LC + 3)  // chunk rows + 3-row conv halo

static __device__ __forceinline__ float silu_f(float v) { return v / (1.f + __expf(-v)); }

// ---------------- K0: per-row rmsnorm scale ----------------
__global__ __launch_bounds__(256) void k_rowscale(const float* __restrict__ inp,
                                                  float* __restrict__ rs) {
  int row = blockIdx.x;
  int t = threadIdx.x;
  float4 xv = *(const float4*)(inp + (size_t)row * HDIM + t * 4);
  float ss = xv.x * xv.x + xv.y * xv.y + xv.z * xv.z + xv.w * xv.w;
  for (int off = 32; off > 0; off >>= 1) ss += __shfl_down(ss, off);
  __shared__ float red[4];
  if ((t & 63) == 0) red[t >> 6] = ss;
  __syncthreads();
  if (t == 0) {
    float tot = red[0] + red[1] + red[2] + red[3];
    rs[row] = rsqrtf(tot * (1.f / HDIM) + 1e-6f);
  }
}

// ---------------- halo: copy last 3 x-rows of previous chunk to rows [0,3) ----------------
__global__ __launch_bounds__(256) void k_halo(float* __restrict__ xgb) {
  int idx = blockIdx.x * 256 + threadIdx.x;  // 2 batches * 3 rows * 2048 cols = 12288
  int b = idx / (3 * DDIM);
  int rem = idx - b * 3 * DDIM;
  int r = rem / DDIM;
  int c = rem - r * DDIM;
  xgb[(size_t)(b * XROWS + r) * 4096 + c] = xgb[(size_t)(b * XROWS + LC + r) * 4096 + c];
}

// ---------------- K1: in_proj GEMM (rmsnorm fused), chunk of 2*LC rows ----------------
__global__ __launch_bounds__(256) void k_gemm1(const float* __restrict__ A,
                                               const float* __restrict__ W,
                                               const float* __restrict__ bias,
                                               const float* __restrict__ rscale,
                                               const float* __restrict__ nw,
                                               float* __restrict__ xgb, int l0) {
  __shared__ float As[16][68];
  __shared__ float Ws[16][68];
  int tid = threadIdx.x;
  int tx = tid & 15, ty = tid >> 4;
  int m0 = blockIdx.y * 64, n0 = blockIdx.x * 64;
  int lm = tid >> 2, lk = (tid & 3) * 4;
  int r = m0 + lm;                                   // 0..511 chunk row
  int gin = ((r >> 8) << 10) + l0 + (r & 255);       // global BL row
  const float* Ag = A + (size_t)gin * HDIM + lk;
  const float* Wg = W + (size_t)(n0 + lm) * HDIM + lk;
  float scale = rscale[gin];
  float c[4][4] = {};
  for (int k0 = 0; k0 < HDIM; k0 += 16) {
    float4 av = *(const float4*)(Ag + k0);
    float4 wv = *(const float4*)(Wg + k0);
    float4 nv = *(const float4*)(nw + k0 + lk);
    float a0 = av.x * scale * nv.x;
    float a1 = av.y * scale * nv.y;
    float a2 = av.z * scale * nv.z;
    float a3 = av.w * scale * nv.w;
    __syncthreads();
    As[lk + 0][lm] = a0; As[lk + 1][lm] = a1;
    As[lk + 2][lm] = a2; As[lk + 3][lm] = a3;
    Ws[lk + 0][lm] = wv.x; Ws[lk + 1][lm] = wv.y;
    Ws[lk + 2][lm] = wv.z; Ws[lk + 3][lm] = wv.w;
    __syncthreads();
#pragma unroll
    for (int kk = 0; kk < 16; kk++) {
      float4 a = *(const float4*)&As[kk][ty * 4];
      float4 w = *(const float4*)&Ws[kk][tx * 4];
      c[0][0] += a.x * w.x; c[0][1] += a.x * w.y; c[0][2] += a.x * w.z; c[0][3] += a.x * w.w;
      c[1][0] += a.y * w.x; c[1][1] += a.y * w.y; c[1][2] += a.y * w.z; c[1][3] += a.y * w.w;
      c[2][0] += a.z * w.x; c[2][1] += a.z * w.y; c[2][2] += a.z * w.z; c[2][3] += a.z * w.w;
      c[3][0] += a.w * w.x; c[3][1] += a.w * w.y; c[3][2] += a.w * w.z; c[3][3] += a.w * w.w;
    }
  }
  int col = n0 + tx * 4;
#pragma unroll
  for (int i = 0; i < 4; i++) {
    int rr = m0 + ty * 4 + i;
    int lout = (rr >> 8) * XROWS + 3 + (rr & 255);   // chunk-local xgb row
#pragma unroll
    for (int j = 0; j < 4; j++) {
      xgb[(size_t)lout * 4096 + col + j] = c[i][j] + bias[col + j];
    }
  }
}

// ---------------- K2: conv+silu (in LDS) then x_proj (96 outs/token) ----------------
__global__ __launch_bounds__(256) void k_xprojc(const float* __restrict__ xgb,
                                                const float* __restrict__ cw,
                                                const float* __restrict__ cb,
                                                const float* __restrict__ w,
                                                const float* __restrict__ b,
                                                float* __restrict__ proj, int l0) {
  __shared__ float row[DDIM];
  int bb = blockIdx.x >> 8, lc = blockIdx.x & 255;
  int gl = l0 + lc;
  int t = threadIdx.x;
  int d = t * 8;
  float acc[8];
#pragma unroll
  for (int i = 0; i < 8; i++) acc[i] = cb[d + i];
  float cwv[8][4];
#pragma unroll
  for (int i = 0; i < 8; i++) {
    float4 v = *(const float4*)(cw + (d + i) * 4);
    cwv[i][0] = v.x; cwv[i][1] = v.y; cwv[i][2] = v.z; cwv[i][3] = v.w;
  }
#pragma unroll
  for (int j = 0; j < 4; j++) {
    if (gl - 3 + j >= 0) {  // causal guard; halo rows valid when this holds
      const float* xr = xgb + (size_t)(bb * XROWS + lc + j) * 4096 + d;
      float4 v0 = *(const float4*)xr;
      float4 v1 = *(const float4*)(xr + 4);
      acc[0] += v0.x * cwv[0][j]; acc[1] += v0.y * cwv[1][j];
      acc[2] += v0.z * cwv[2][j]; acc[3] += v0.w * cwv[3][j];
      acc[4] += v1.x * cwv[4][j]; acc[5] += v1.y * cwv[5][j];
      acc[6] += v1.z * cwv[6][j]; acc[7] += v1.w * cwv[7][j];
    }
  }
#pragma unroll
  for (int i = 0; i < 8; i++) row[d + i] = silu_f(acc[i]);
  __syncthreads();
  int wv = t >> 6, lane = t & 63;
  for (int o = wv; o < 96; o += 4) {
    const float* wr = w + (size_t)o * DDIM;
    float s = 0.f;
    for (int k = lane; k < DDIM; k += 64) s += row[k] * wr[k];
    s += __shfl_xor(s, 32); s += __shfl_xor(s, 16);
    s += __shfl_xor(s, 8);  s += __shfl_xor(s, 4);
    s += __shfl_xor(s, 2);  s += __shfl_xor(s, 1);
    if (lane == 0) proj[(size_t)((bb << 10) + gl) * 96 + o] = s + b[o];
  }
}

// ---------------- K3: parallel selective scan (prefix-sum formulation) ----------------
// One block per (b,d). cum_l = A_n*D_l with D_l = prefix(delta); S via per-wave shfl scans.
__global__ __launch_bounds__(256) void k_scan(const float* __restrict__ proj,
                                              const float* __restrict__ xgb,
                                              const float* __restrict__ cw,
                                              const float* __restrict__ cb,
                                              const float* __restrict__ dtw,
                                              const float* __restrict__ dtb,
                                              const float* __restrict__ alog,
                                              const float* __restrict__ dparam,
                                              const float* __restrict__ cs,
                                              float* __restrict__ cumA,   // [4096] carried D
                                              float* __restrict__ SA,     // [65536] carried S per n
                                              float* __restrict__ yb, int l0) {
  __shared__ float xs[XROWS];      // x column incl. 3-row halo
  __shared__ float xcs[LC];        // conv+silu output
  __shared__ float ds[LC];         // delta
  __shared__ float Dl[LC];         // inclusive prefix of delta
  __shared__ float dtw_s[64];
  __shared__ float Bc[16][LC];
  __shared__ float Cc[16][LC];
  __shared__ float ys[4][LC];

  int t = threadIdx.x;
  int cidx = blockIdx.x;           // (b,d)
  int b = cidx >> 11;
  int d = cidx & (DDIM - 1);
  const float* pr = proj + ((size_t)(b << 10) + l0) * 96;

  // stage x column (with halo)
  xs[t] = (l0 == 0 && t < 3) ? 0.f : xgb[(size_t)(b * XROWS + t) * 4096 + d];
  if (t < 3) xs[LC + t] = xgb[(size_t)(b * XROWS + LC + t) * 4096 + d];
  if (t < 64) dtw_s[t] = dtw[(size_t)d * 64 + t];
  // stage B, C
  {
    const float4* bp = (const float4*)(pr + (size_t)t * 96 + 64);
    float4 b0 = bp[0], b1 = bp[1], b2 = bp[2], b3 = bp[3];
    float4 c0 = bp[4], c1 = bp[5], c2 = bp[6], c3 = bp[7];
    Bc[0][t] = b0.x; Bc[1][t] = b0.y; Bc[2][t] = b0.z; Bc[3][t] = b0.w;
    Bc[4][t] = b1.x; Bc[5][t] = b1.y; Bc[6][t] = b1.z; Bc[7][t] = b1.w;
    Bc[8][t] = b2.x; Bc[9][t] = b2.y; Bc[10][t] = b2.z; Bc[11][t] = b2.w;
    Bc[12][t] = b3.x; Bc[13][t] = b3.y; Bc[14][t] = b3.z; Bc[15][t] = b3.w;
    Cc[0][t] = c0.x; Cc[1][t] = c0.y; Cc[2][t] = c0.z; Cc[3][t] = c0.w;
    Cc[4][t] = c1.x; Cc[5][t] = c1.y; Cc[6][t] = c1.z; Cc[7][t] = c1.w;
    Cc[8][t] = c2.x; Cc[9][t] = c2.y; Cc[10][t] = c2.z; Cc[11][t] = c2.w;
    Cc[12][t] = c3.x; Cc[13][t] = c3.y; Cc[14][t] = c3.z; Cc[15][t] = c3.w;
  }
  __syncthreads();

  // conv + silu (thread t -> token t)
  {
    float4 cwv = *(const float4*)(cw + d * 4);
    float v = cb[d] + cwv.w * xs[t + 3] + cwv.z * xs[t + 2] + cwv.y * xs[t + 1] + cwv.x * xs[t];
    xcs[t] = silu_f(v);
  }
  // delta (thread t -> token t): 64-dot + softplus
  {
    float acc = dtb[d];
    const float4* pv = (const float4*)(pr + (size_t)t * 96);
#pragma unroll
    for (int k = 0; k < 16; k++) {
      float4 v = pv[k];
      acc += v.x * dtw_s[k * 4 + 0] + v.y * dtw_s[k * 4 + 1] +
             v.z * dtw_s[k * 4 + 2] + v.w * dtw_s[k * 4 + 3];
    }
    ds[t] = (acc > 20.f) ? acc : log1pf(__expf(acc));
  }
  __syncthreads();

  // Hillis-Steele inclusive prefix sum of ds -> Dl
  Dl[t] = ds[t];
  __syncthreads();
#pragma unroll
  for (int off = 1; off < LC; off <<= 1) {
    float v = (t >= off) ? Dl[t - off] : 0.f;
    __syncthreads();
    Dl[t] += v;
    __syncthreads();
  }

  int wv = t >> 6, lane = t & 63;
  float Dc = (l0 == 0) ? 0.f : cumA[cidx];
  float yacc0 = 0.f, yacc1 = 0.f, yacc2 = 0.f, yacc3 = 0.f;

  for (int r = 0; r < 4; r++) {
    int n = wv * 4 + r;
    float An = -__expf(alog[d * NST + n]);
    float state = cs[(size_t)(b * DDIM + d) * NST + n];
    int ci = (cidx << 4) | n;
    float Soff = (l0 == 0) ? 0.f : SA[ci];
#pragma unroll
    for (int s = 0; s < 4; s++) {
      int l = (s << 6) + lane;
      float dsl = ds[l];
      float De = (l == 0) ? 0.f : Dl[l - 1];
      float Di = Dl[l];
      float Pprev = __expf(An * (Dc + De));
      float P = __expf(An * (Dc + Di));
      float w = (dsl * Bc[n][l] * xcs[l]) / fmaxf(Pprev, 1e-10f);
      // inclusive wave scan of w
#pragma unroll
      for (int off = 1; off < 64; off <<= 1) {
        float u = __shfl_up(w, off);
        if (lane >= off) w += u;
      }
      float S = Soff + w;
      float h = S * Pprev + state * P;
      float contrib = h * Cc[n][l];
      if (s == 0) yacc0 += contrib;
      else if (s == 1) yacc1 += contrib;
      else if (s == 2) yacc2 += contrib;
      else yacc3 += contrib;
      Soff = __shfl(S, 63);
    }
    if (lane == 0) SA[ci] = Soff;
  }
  ys[wv][lane] = yacc0;
  ys[wv][64 + lane] = yacc1;
  ys[wv][128 + lane] = yacc2;
  ys[wv][192 + lane] = yacc3;
  if (t == 0) cumA[cidx] = Dc + Dl[LC - 1];
  __syncthreads();

  // final: y = sum over waves + D-term, gate, write
  {
    float y = ys[0][t] + ys[1][t] + ys[2][t] + ys[3][t] + xcs[t] * dparam[d];
    float g = xgb[(size_t)(b * XROWS + 3 + t) * 4096 + DDIM + d];
    yb[(size_t)((b << 8) + t) * DDIM + d] = y * silu_f(g);
  }
}

// ---------------- K4: out_proj GEMM + bias + residual ----------------
__global__ __launch_bounds__(256) void k_gemm2(const float* __restrict__ A,  // yb [512][2048]
                                               const float* __restrict__ W,
                                               const float* __restrict__ bias,
                                               const float* __restrict__ resid,
                                               float* __restrict__ out, int l0) {
  __shared__ float As[16][68];
  __shared__ float Ws[16][68];
  int tid = threadIdx.x;
  int tx = tid & 15, ty = tid >> 4;
  int m0 = blockIdx.y * 64, n0 = blockIdx.x * 64;
  int lm = tid >> 2, lk = (tid & 3) * 4;
  const float* Ag = A + (size_t)(m0 + lm) * DDIM + lk;
  const float* Wg = W + (size_t)(n0 + lm) * DDIM + lk;
  float c[4][4] = {};
  for (int k0 = 0; k0 < DDIM; k0 += 16) {
    float4 av = *(const float4*)(Ag + k0);
    float4 wv = *(const float4*)(Wg + k0);
    __syncthreads();
    As[lk + 0][lm] = av.x; As[lk + 1][lm] = av.y;
    As[lk + 2][lm] = av.z; As[lk + 3][lm] = av.w;
    Ws[lk + 0][lm] = wv.x; Ws[lk + 1][lm] = wv.y;
    Ws[lk + 2][lm] = wv.z; Ws[lk + 3][lm] = wv.w;
    __syncthreads();
#pragma unroll
    for (int kk = 0; kk < 16; kk++) {
      float4 a = *(const float4*)&As[kk][ty * 4];
      float4 w = *(const float4*)&Ws[kk][tx * 4];
      c[0][0] += a.x * w.x; c[0][1] += a.x * w.y; c[0][2] += a.x * w.z; c[0][3] += a.x * w.w;
      c[1][0] += a.y * w.x; c[1][1] += a.y * w.y; c[1][2] += a.y * w.z; c[1][3] += a.y * w.w;
      c[2][0] += a.z * w.x; c[2][1] += a.z * w.y; c[2][2] += a.z * w.z; c[2][3] += a.z * w.w;
      c[3][0] += a.w * w.x; c[3][1] += a.w * w.y; c[3][2] += a.w * w.z; c[3][3] += a.w * w.w;
    }
  }
  int col = n0 + tx * 4;
#pragma unroll
  for (int i = 0; i < 4; i++) {
    int rr = m0 + ty * 4 + i;
    int gout = ((rr >> 8) << 10) + l0 + (rr & 255);
#pragma unroll
    for (int j = 0; j < 4; j++) {
      out[(size_t)gout * HDIM + col + j] =
          c[i][j] + bias[col + j] + resid[(size_t)gout * HDIM + col + j];
    }
  }
}

extern "C" void kernel_launch(void* const* d_in, const int* in_sizes, int n_in,
                              void* d_out, int out_size, void* d_ws, size_t ws_size,
                              hipStream_t stream) {
  const float* inp    = (const float*)d_in[0];
  const float* cstate = (const float*)d_in[1];
  const float* norm_w = (const float*)d_in[2];
  const float* w1     = (const float*)d_in[3];
  const float* b1     = (const float*)d_in[4];
  const float* convw  = (const float*)d_in[5];
  const float* convb  = (const float*)d_in[6];
  const float* xpw    = (const float*)d_in[7];
  const float* xpb    = (const float*)d_in[8];
  const float* dtw    = (const float*)d_in[9];
  const float* dtb    = (const float*)d_in[10];
  const float* alog   = (const float*)d_in[11];
  const float* dparam = (const float*)d_in[12];
  const float* wo     = (const float*)d_in[13];
  const float* bo     = (const float*)d_in[14];
  float* out = (float*)d_out;

  // workspace layout, 14,316,544 B total (proven fits)
  char* wsb = (char*)d_ws;
  float* rscale = (float*)(wsb + 0);          //     8,192 B
  float* proj   = (float*)(wsb + 8192);       //   786,432 B  [2048][96]
  float* cumA   = (float*)(wsb + 794624);     //    16,384 B used  [4096]
  float* SA     = (float*)(wsb + 1056768);    //   262,144 B  [65536]
  float* xgb    = (float*)(wsb + 1581056);    // 8,486,912 B  [2][259][4096]
  float* yb     = (float*)(wsb + 10067968);   // 4,194,304 B  [2][256][2048]

  k_rowscale<<<BL, 256, 0, stream>>>(inp, rscale);
  for (int c = 0; c < 4; c++) {
    int l0 = c * LC;
    if (c > 0) k_halo<<<48, 256, 0, stream>>>(xgb);
    k_gemm1<<<dim3(64, 8), 256, 0, stream>>>(inp, w1, b1, rscale, norm_w, xgb, l0);
    k_xprojc<<<2 * LC, 256, 0, stream>>>(xgb, convw, convb, xpw, xpb, proj, l0);
    k_scan<<<2 * DDIM, 256, 0, stream>>>(proj, xgb, convw, convb, dtw, dtb,
                                         alog, dparam, cstate, cumA, SA, yb, l0);
    k_gemm2<<<dim3(16, 8), 256, 0, stream>>>(yb, wo, bo, inp, out, l0);
  }
}

// Round 6
// 1182.544 us; speedup vs baseline: 2.5091x; 1.5916x over previous
//
#include <hip/hip_runtime.h>
#include <stdint.h>

#define LSEQ 1024
#define HDIM 1024
#define DDIM 2048
#define BL 2048
#define NST 16
#define LC 256          // chunk length in tokens
#define XROWS (LC + 3)  // chunk rows + 3-row conv halo

static __device__ __forceinline__ float silu_f(float v) { return v / (1.f + __expf(-v)); }

// ---------------- K0: per-row rmsnorm scale ----------------
__global__ __launch_bounds__(256) void k_rowscale(const float* __restrict__ inp,
                                                  float* __restrict__ rs) {
  int row = blockIdx.x;
  int t = threadIdx.x;
  float4 xv = *(const float4*)(inp + (size_t)row * HDIM + t * 4);
  float ss = xv.x * xv.x + xv.y * xv.y + xv.z * xv.z + xv.w * xv.w;
  for (int off = 32; off > 0; off >>= 1) ss += __shfl_down(ss, off);
  __shared__ float red[4];
  if ((t & 63) == 0) red[t >> 6] = ss;
  __syncthreads();
  if (t == 0) {
    float tot = red[0] + red[1] + red[2] + red[3];
    rs[row] = rsqrtf(tot * (1.f / HDIM) + 1e-6f);
  }
}

// ---------------- halo: copy last 3 x-rows of previous chunk to rows [0,3) ----------------
__global__ __launch_bounds__(256) void k_halo(float* __restrict__ xgb) {
  int idx = blockIdx.x * 256 + threadIdx.x;  // 2 batches * 3 rows * 2048 cols = 12288
  int b = idx / (3 * DDIM);
  int rem = idx - b * 3 * DDIM;
  int r = rem / DDIM;
  int c = rem - r * DDIM;
  xgb[(size_t)(b * XROWS + r) * 4096 + c] = xgb[(size_t)(b * XROWS + LC + r) * 4096 + c];
}

// ---------------- K1: in_proj GEMM (rmsnorm fused), chunk of 2*LC rows ----------------
__global__ __launch_bounds__(256) void k_gemm1(const float* __restrict__ A,
                                               const float* __restrict__ W,
                                               const float* __restrict__ bias,
                                               const float* __restrict__ rscale,
                                               const float* __restrict__ nw,
                                               float* __restrict__ xgb, int l0) {
  __shared__ float As[16][68];
  __shared__ float Ws[16][68];
  int tid = threadIdx.x;
  int tx = tid & 15, ty = tid >> 4;
  int m0 = blockIdx.y * 64, n0 = blockIdx.x * 64;
  int lm = tid >> 2, lk = (tid & 3) * 4;
  int r = m0 + lm;                                   // 0..511 chunk row
  int gin = ((r >> 8) << 10) + l0 + (r & 255);       // global BL row
  const float* Ag = A + (size_t)gin * HDIM + lk;
  const float* Wg = W + (size_t)(n0 + lm) * HDIM + lk;
  float scale = rscale[gin];
  float c[4][4] = {};
  for (int k0 = 0; k0 < HDIM; k0 += 16) {
    float4 av = *(const float4*)(Ag + k0);
    float4 wv = *(const float4*)(Wg + k0);
    float4 nv = *(const float4*)(nw + k0 + lk);
    float a0 = av.x * scale * nv.x;
    float a1 = av.y * scale * nv.y;
    float a2 = av.z * scale * nv.z;
    float a3 = av.w * scale * nv.w;
    __syncthreads();
    As[lk + 0][lm] = a0; As[lk + 1][lm] = a1;
    As[lk + 2][lm] = a2; As[lk + 3][lm] = a3;
    Ws[lk + 0][lm] = wv.x; Ws[lk + 1][lm] = wv.y;
    Ws[lk + 2][lm] = wv.z; Ws[lk + 3][lm] = wv.w;
    __syncthreads();
#pragma unroll
    for (int kk = 0; kk < 16; kk++) {
      float4 a = *(const float4*)&As[kk][ty * 4];
      float4 w = *(const float4*)&Ws[kk][tx * 4];
      c[0][0] += a.x * w.x; c[0][1] += a.x * w.y; c[0][2] += a.x * w.z; c[0][3] += a.x * w.w;
      c[1][0] += a.y * w.x; c[1][1] += a.y * w.y; c[1][2] += a.y * w.z; c[1][3] += a.y * w.w;
      c[2][0] += a.z * w.x; c[2][1] += a.z * w.y; c[2][2] += a.z * w.z; c[2][3] += a.z * w.w;
      c[3][0] += a.w * w.x; c[3][1] += a.w * w.y; c[3][2] += a.w * w.z; c[3][3] += a.w * w.w;
    }
  }
  int col = n0 + tx * 4;
#pragma unroll
  for (int i = 0; i < 4; i++) {
    int rr = m0 + ty * 4 + i;
    int lout = (rr >> 8) * XROWS + 3 + (rr & 255);   // chunk-local xgb row
#pragma unroll
    for (int j = 0; j < 4; j++) {
      xgb[(size_t)lout * 4096 + col + j] = c[i][j] + bias[col + j];
    }
  }
}

// ---------------- K2: conv+silu (in LDS) then x_proj (96 outs/token) ----------------
__global__ __launch_bounds__(256) void k_xprojc(const float* __restrict__ xgb,
                                                const float* __restrict__ cw,
                                                const float* __restrict__ cb,
                                                const float* __restrict__ w,
                                                const float* __restrict__ b,
                                                float* __restrict__ proj, int l0) {
  __shared__ float row[DDIM];
  int bb = blockIdx.x >> 8, lc = blockIdx.x & 255;
  int gl = l0 + lc;
  int t = threadIdx.x;
  int d = t * 8;
  float acc[8];
#pragma unroll
  for (int i = 0; i < 8; i++) acc[i] = cb[d + i];
  float cwv[8][4];
#pragma unroll
  for (int i = 0; i < 8; i++) {
    float4 v = *(const float4*)(cw + (d + i) * 4);
    cwv[i][0] = v.x; cwv[i][1] = v.y; cwv[i][2] = v.z; cwv[i][3] = v.w;
  }
#pragma unroll
  for (int j = 0; j < 4; j++) {
    if (gl - 3 + j >= 0) {  // causal guard; halo rows valid when this holds
      const float* xr = xgb + (size_t)(bb * XROWS + lc + j) * 4096 + d;
      float4 v0 = *(const float4*)xr;
      float4 v1 = *(const float4*)(xr + 4);
      acc[0] += v0.x * cwv[0][j]; acc[1] += v0.y * cwv[1][j];
      acc[2] += v0.z * cwv[2][j]; acc[3] += v0.w * cwv[3][j];
      acc[4] += v1.x * cwv[4][j]; acc[5] += v1.y * cwv[5][j];
      acc[6] += v1.z * cwv[6][j]; acc[7] += v1.w * cwv[7][j];
    }
  }
#pragma unroll
  for (int i = 0; i < 8; i++) row[d + i] = silu_f(acc[i]);
  __syncthreads();
  int wv = t >> 6, lane = t & 63;
  const float4* row4 = (const float4*)row;
  for (int o = wv; o < 96; o += 4) {
    const float4* wr4 = (const float4*)(w + (size_t)o * DDIM);
    float s0 = 0.f, s1 = 0.f, s2 = 0.f, s3 = 0.f;
#pragma unroll
    for (int k4 = 0; k4 < 8; k4++) {          // constant trip count -> full unroll, 8 loads in flight
      int idx = (k4 << 6) + lane;             // lane-contiguous float4 -> dwordx4 coalesced
      float4 wv4 = wr4[idx];
      float4 rv4 = row4[idx];
      s0 += rv4.x * wv4.x; s1 += rv4.y * wv4.y;
      s2 += rv4.z * wv4.z; s3 += rv4.w * wv4.w;
    }
    float s = (s0 + s1) + (s2 + s3);
    s += __shfl_xor(s, 32); s += __shfl_xor(s, 16);
    s += __shfl_xor(s, 8);  s += __shfl_xor(s, 4);
    s += __shfl_xor(s, 2);  s += __shfl_xor(s, 1);
    if (lane == 0) proj[(size_t)((bb << 10) + gl) * 96 + o] = s + b[o];
  }
}

// ---------------- K3: parallel selective scan (prefix-sum formulation) ----------------
// One block per (b,d). cum_l = A_n*D_l with D_l = prefix(delta); S via per-wave shfl scans.
__global__ __launch_bounds__(256) void k_scan(const float* __restrict__ proj,
                                              const float* __restrict__ xgb,
                                              const float* __restrict__ cw,
                                              const float* __restrict__ cb,
                                              const float* __restrict__ dtw,
                                              const float* __restrict__ dtb,
                                              const float* __restrict__ alog,
                                              const float* __restrict__ dparam,
                                              const float* __restrict__ cs,
                                              float* __restrict__ cumA,   // [4096] carried D
                                              float* __restrict__ SA,     // [65536] carried S per n
                                              float* __restrict__ yb, int l0) {
  __shared__ float xs[XROWS];      // x column incl. 3-row halo
  __shared__ float xcs[LC];        // conv+silu output
  __shared__ float ds[LC];         // delta
  __shared__ float Dl[LC];         // inclusive prefix of delta
  __shared__ float dtw_s[64];
  __shared__ float Bc[16][LC];
  __shared__ float Cc[16][LC];
  __shared__ float ys[4][LC];

  int t = threadIdx.x;
  int cidx = blockIdx.x;           // (b,d)
  int b = cidx >> 11;
  int d = cidx & (DDIM - 1);
  const float* pr = proj + ((size_t)(b << 10) + l0) * 96;

  // stage x column (with halo)
  xs[t] = (l0 == 0 && t < 3) ? 0.f : xgb[(size_t)(b * XROWS + t) * 4096 + d];
  if (t < 3) xs[LC + t] = xgb[(size_t)(b * XROWS + LC + t) * 4096 + d];
  if (t < 64) dtw_s[t] = dtw[(size_t)d * 64 + t];
  // stage B, C
  {
    const float4* bp = (const float4*)(pr + (size_t)t * 96 + 64);
    float4 b0 = bp[0], b1 = bp[1], b2 = bp[2], b3 = bp[3];
    float4 c0 = bp[4], c1 = bp[5], c2 = bp[6], c3 = bp[7];
    Bc[0][t] = b0.x; Bc[1][t] = b0.y; Bc[2][t] = b0.z; Bc[3][t] = b0.w;
    Bc[4][t] = b1.x; Bc[5][t] = b1.y; Bc[6][t] = b1.z; Bc[7][t] = b1.w;
    Bc[8][t] = b2.x; Bc[9][t] = b2.y; Bc[10][t] = b2.z; Bc[11][t] = b2.w;
    Bc[12][t] = b3.x; Bc[13][t] = b3.y; Bc[14][t] = b3.z; Bc[15][t] = b3.w;
    Cc[0][t] = c0.x; Cc[1][t] = c0.y; Cc[2][t] = c0.z; Cc[3][t] = c0.w;
    Cc[4][t] = c1.x; Cc[5][t] = c1.y; Cc[6][t] = c1.z; Cc[7][t] = c1.w;
    Cc[8][t] = c2.x; Cc[9][t] = c2.y; Cc[10][t] = c2.z; Cc[11][t] = c2.w;
    Cc[12][t] = c3.x; Cc[13][t] = c3.y; Cc[14][t] = c3.z; Cc[15][t] = c3.w;
  }
  __syncthreads();

  // conv + silu (thread t -> token t)
  {
    float4 cwv = *(const float4*)(cw + d * 4);
    float v = cb[d] + cwv.w * xs[t + 3] + cwv.z * xs[t + 2] + cwv.y * xs[t + 1] + cwv.x * xs[t];
    xcs[t] = silu_f(v);
  }
  // delta (thread t -> token t): 64-dot + softplus
  {
    float acc = dtb[d];
    const float4* pv = (const float4*)(pr + (size_t)t * 96);
#pragma unroll
    for (int k = 0; k < 16; k++) {
      float4 v = pv[k];
      acc += v.x * dtw_s[k * 4 + 0] + v.y * dtw_s[k * 4 + 1] +
             v.z * dtw_s[k * 4 + 2] + v.w * dtw_s[k * 4 + 3];
    }
    ds[t] = (acc > 20.f) ? acc : log1pf(__expf(acc));
  }
  __syncthreads();

  // Hillis-Steele inclusive prefix sum of ds -> Dl
  Dl[t] = ds[t];
  __syncthreads();
#pragma unroll
  for (int off = 1; off < LC; off <<= 1) {
    float v = (t >= off) ? Dl[t - off] : 0.f;
    __syncthreads();
    Dl[t] += v;
    __syncthreads();
  }

  int wv = t >> 6, lane = t & 63;
  float Dc = (l0 == 0) ? 0.f : cumA[cidx];
  float yacc0 = 0.f, yacc1 = 0.f, yacc2 = 0.f, yacc3 = 0.f;

  for (int r = 0; r < 4; r++) {
    int n = wv * 4 + r;
    float An = -__expf(alog[d * NST + n]);
    float state = cs[(size_t)(b * DDIM + d) * NST + n];
    int ci = (cidx << 4) | n;
    float Soff = (l0 == 0) ? 0.f : SA[ci];
#pragma unroll
    for (int s = 0; s < 4; s++) {
      int l = (s << 6) + lane;
      float dsl = ds[l];
      float De = (l == 0) ? 0.f : Dl[l - 1];
      float Di = Dl[l];
      float Pprev = __expf(An * (Dc + De));
      float P = __expf(An * (Dc + Di));
      float w = (dsl * Bc[n][l] * xcs[l]) / fmaxf(Pprev, 1e-10f);
      // inclusive wave scan of w
#pragma unroll
      for (int off = 1; off < 64; off <<= 1) {
        float u = __shfl_up(w, off);
        if (lane >= off) w += u;
      }
      float S = Soff + w;
      float h = S * Pprev + state * P;
      float contrib = h * Cc[n][l];
      if (s == 0) yacc0 += contrib;
      else if (s == 1) yacc1 += contrib;
      else if (s == 2) yacc2 += contrib;
      else yacc3 += contrib;
      Soff = __shfl(S, 63);
    }
    if (lane == 0) SA[ci] = Soff;
  }
  ys[wv][lane] = yacc0;
  ys[wv][64 + lane] = yacc1;
  ys[wv][128 + lane] = yacc2;
  ys[wv][192 + lane] = yacc3;
  if (t == 0) cumA[cidx] = Dc + Dl[LC - 1];
  __syncthreads();

  // final: y = sum over waves + D-term, gate, write
  {
    float y = ys[0][t] + ys[1][t] + ys[2][t] + ys[3][t] + xcs[t] * dparam[d];
    float g = xgb[(size_t)(b * XROWS + 3 + t) * 4096 + DDIM + d];
    yb[(size_t)((b << 8) + t) * DDIM + d] = y * silu_f(g);
  }
}

// ---------------- K4: out_proj GEMM + bias + residual ----------------
__global__ __launch_bounds__(256) void k_gemm2(const float* __restrict__ A,  // yb [512][2048]
                                               const float* __restrict__ W,
                                               const float* __restrict__ bias,
                                               const float* __restrict__ resid,
                                               float* __restrict__ out, int l0) {
  __shared__ float As[16][68];
  __shared__ float Ws[16][68];
  int tid = threadIdx.x;
  int tx = tid & 15, ty = tid >> 4;
  int m0 = blockIdx.y * 64, n0 = blockIdx.x * 64;
  int lm = tid >> 2, lk = (tid & 3) * 4;
  const float* Ag = A + (size_t)(m0 + lm) * DDIM + lk;
  const float* Wg = W + (size_t)(n0 + lm) * DDIM + lk;
  float c[4][4] = {};
  for (int k0 = 0; k0 < DDIM; k0 += 16) {
    float4 av = *(const float4*)(Ag + k0);
    float4 wv = *(const float4*)(Wg + k0);
    __syncthreads();
    As[lk + 0][lm] = av.x; As[lk + 1][lm] = av.y;
    As[lk + 2][lm] = av.z; As[lk + 3][lm] = av.w;
    Ws[lk + 0][lm] = wv.x; Ws[lk + 1][lm] = wv.y;
    Ws[lk + 2][lm] = wv.z; Ws[lk + 3][lm] = wv.w;
    __syncthreads();
#pragma unroll
    for (int kk = 0; kk < 16; kk++) {
      float4 a = *(const float4*)&As[kk][ty * 4];
      float4 w = *(const float4*)&Ws[kk][tx * 4];
      c[0][0] += a.x * w.x; c[0][1] += a.x * w.y; c[0][2] += a.x * w.z; c[0][3] += a.x * w.w;
      c[1][0] += a.y * w.x; c[1][1] += a.y * w.y; c[1][2] += a.y * w.z; c[1][3] += a.y * w.w;
      c[2][0] += a.z * w.x; c[2][1] += a.z * w.y; c[2][2] += a.z * w.z; c[2][3] += a.z * w.w;
      c[3][0] += a.w * w.x; c[3][1] += a.w * w.y; c[3][2] += a.w * w.z; c[3][3] += a.w * w.w;
    }
  }
  int col = n0 + tx * 4;
#pragma unroll
  for (int i = 0; i < 4; i++) {
    int rr = m0 + ty * 4 + i;
    int gout = ((rr >> 8) << 10) + l0 + (rr & 255);
#pragma unroll
    for (int j = 0; j < 4; j++) {
      out[(size_t)gout * HDIM + col + j] =
          c[i][j] + bias[col + j] + resid[(size_t)gout * HDIM + col + j];
    }
  }
}

extern "C" void kernel_launch(void* const* d_in, const int* in_sizes, int n_in,
                              void* d_out, int out_size, void* d_ws, size_t ws_size,
                              hipStream_t stream) {
  const float* inp    = (const float*)d_in[0];
  const float* cstate = (const float*)d_in[1];
  const float* norm_w = (const float*)d_in[2];
  const float* w1     = (const float*)d_in[3];
  const float* b1     = (const float*)d_in[4];
  const float* convw  = (const float*)d_in[5];
  const float* convb  = (const float*)d_in[6];
  const float* xpw    = (const float*)d_in[7];
  const float* xpb    = (const float*)d_in[8];
  const float* dtw    = (const float*)d_in[9];
  const float* dtb    = (const float*)d_in[10];
  const float* alog   = (const float*)d_in[11];
  const float* dparam = (const float*)d_in[12];
  const float* wo     = (const float*)d_in[13];
  const float* bo     = (const float*)d_in[14];
  float* out = (float*)d_out;

  // workspace layout, 14,316,544 B total (proven fits)
  char* wsb = (char*)d_ws;
  float* rscale = (float*)(wsb + 0);          //     8,192 B
  float* proj   = (float*)(wsb + 8192);       //   786,432 B  [2048][96]
  float* cumA   = (float*)(wsb + 794624);     //    16,384 B used  [4096]
  float* SA     = (float*)(wsb + 1056768);    //   262,144 B  [65536]
  float* xgb    = (float*)(wsb + 1581056);    // 8,486,912 B  [2][259][4096]
  float* yb     = (float*)(wsb + 10067968);   // 4,194,304 B  [2][256][2048]

  k_rowscale<<<BL, 256, 0, stream>>>(inp, rscale);
  for (int c = 0; c < 4; c++) {
    int l0 = c * LC;
    if (c > 0) k_halo<<<48, 256, 0, stream>>>(xgb);
    k_gemm1<<<dim3(64, 8), 256, 0, stream>>>(inp, w1, b1, rscale, norm_w, xgb, l0);
    k_xprojc<<<2 * LC, 256, 0, stream>>>(xgb, convw, convb, xpw, xpb, proj, l0);
    k_scan<<<2 * DDIM, 256, 0, stream>>>(proj, xgb, convw, convb, dtw, dtb,
                                         alog, dparam, cstate, cumA, SA, yb, l0);
    k_gemm2<<<dim3(16, 8), 256, 0, stream>>>(yb, wo, bo, inp, out, l0);
  }
}

// Round 7
// 713.713 us; speedup vs baseline: 4.1573x; 1.6569x over previous
//
#include <hip/hip_runtime.h>
#include <stdint.h>

#define LSEQ 1024
#define HDIM 1024
#define DDIM 2048
#define BL 2048
#define NST 16
#define LC 256          // chunk length in tokens
#define XROWS (LC + 3)  // chunk rows + 3-row conv halo

typedef unsigned short u16;
typedef __attribute__((ext_vector_type(8))) short bf16x8;
typedef __attribute__((ext_vector_type(4))) float f32x4;

static __device__ __forceinline__ float silu_f(float v) { return v / (1.f + __expf(-v)); }
static __device__ __forceinline__ u16 f2bf(float f) {
  union { float f; unsigned int i; } c; c.f = f;
  unsigned int r = c.i + 0x7fffu + ((c.i >> 16) & 1u);
  return (u16)(r >> 16);
}

// ---------------- cast fp32 -> bf16 (weights, once per launch) ----------------
__global__ __launch_bounds__(256) void k_castw(const float* __restrict__ src,
                                               u16* __restrict__ dst) {
  int idx = blockIdx.x * 256 + threadIdx.x;
  float4 v = ((const float4*)src)[idx];
  ushort4 o;
  o.x = f2bf(v.x); o.y = f2bf(v.y); o.z = f2bf(v.z); o.w = f2bf(v.w);
  ((ushort4*)dst)[idx] = o;
}

// ---------------- rmsnorm + cast: xnb[row] = bf16(inp*scale*norm_w) ----------------
__global__ __launch_bounds__(256) void k_normcast(const float* __restrict__ inp,
                                                  const float* __restrict__ nw,
                                                  u16* __restrict__ xnb) {
  int row = blockIdx.x;
  int t = threadIdx.x;
  float4 xv = *(const float4*)(inp + (size_t)row * HDIM + t * 4);
  float ss = xv.x * xv.x + xv.y * xv.y + xv.z * xv.z + xv.w * xv.w;
  for (int off = 32; off > 0; off >>= 1) ss += __shfl_down(ss, off);
  __shared__ float red[4];
  if ((t & 63) == 0) red[t >> 6] = ss;
  __syncthreads();
  float tot = red[0] + red[1] + red[2] + red[3];
  float scale = rsqrtf(tot * (1.f / HDIM) + 1e-6f);
  float4 nv = *(const float4*)(nw + t * 4);
  ushort4 o;
  o.x = f2bf(xv.x * scale * nv.x); o.y = f2bf(xv.y * scale * nv.y);
  o.z = f2bf(xv.z * scale * nv.z); o.w = f2bf(xv.w * scale * nv.w);
  *(ushort4*)(xnb + (size_t)row * HDIM + t * 4) = o;
}

// ---------------- halo: copy last 3 x-rows of previous chunk to rows [0,3) ----------------
__global__ __launch_bounds__(256) void k_halo(float* __restrict__ xgb) {
  int idx = blockIdx.x * 256 + threadIdx.x;  // 2 batches * 3 rows * 2048 cols = 12288
  int b = idx / (3 * DDIM);
  int rem = idx - b * 3 * DDIM;
  int r = rem / DDIM;
  int c = rem - r * DDIM;
  xgb[(size_t)(b * XROWS + r) * 4096 + c] = xgb[(size_t)(b * XROWS + LC + r) * 4096 + c];
}

// ---------------- K1: in_proj MFMA GEMM: xg = xnb . w1b^T + b1 (fp32 out) ----------------
// 64x64 tile, BK=32, 4 waves; wave w does rows [16w,16w+16), 4 n-frags.
__global__ __launch_bounds__(256) void k_gemm1_mfma(const u16* __restrict__ A,   // [2048][1024] bf16
                                                    const u16* __restrict__ W,   // [4096][1024] bf16
                                                    const float* __restrict__ bias,
                                                    float* __restrict__ xgb, int l0) {
  __shared__ u16 Asm[64 * 40];
  __shared__ u16 Wsm[64 * 40];
  int t = threadIdx.x;
  int m0 = blockIdx.y * 64, n0 = blockIdx.x * 64;
  int srow = t >> 2, koff = (t & 3) * 8;
  int r = m0 + srow;
  int gin = ((r >> 8) << 10) + l0 + (r & 255);      // chunk row -> global BL row
  const u16* Ag = A + (size_t)gin * HDIM + koff;
  const u16* Wg = W + (size_t)(n0 + srow) * HDIM + koff;
  int w = t >> 6, lane = t & 63;
  int quad = lane >> 4, mr = lane & 15;
  f32x4 z = {0.f, 0.f, 0.f, 0.f};
  f32x4 acc0 = z, acc1 = z, acc2 = z, acc3 = z;
  const u16* arp = &Asm[(16 * w + mr) * 40 + quad * 8];
  const u16* brp = &Wsm[mr * 40 + quad * 8];
  for (int k0 = 0; k0 < HDIM; k0 += 32) {
    uint4 av = *(const uint4*)(Ag + k0);
    uint4 wv = *(const uint4*)(Wg + k0);
    __syncthreads();
    *(uint4*)(&Asm[srow * 40 + koff]) = av;
    *(uint4*)(&Wsm[srow * 40 + koff]) = wv;
    __syncthreads();
    bf16x8 af = *(const bf16x8*)arp;
    bf16x8 b0 = *(const bf16x8*)(brp);
    bf16x8 b1 = *(const bf16x8*)(brp + 16 * 40);
    bf16x8 b2 = *(const bf16x8*)(brp + 32 * 40);
    bf16x8 b3 = *(const bf16x8*)(brp + 48 * 40);
    acc0 = __builtin_amdgcn_mfma_f32_16x16x32_bf16(af, b0, acc0, 0, 0, 0);
    acc1 = __builtin_amdgcn_mfma_f32_16x16x32_bf16(af, b1, acc1, 0, 0, 0);
    acc2 = __builtin_amdgcn_mfma_f32_16x16x32_bf16(af, b2, acc2, 0, 0, 0);
    acc3 = __builtin_amdgcn_mfma_f32_16x16x32_bf16(af, b3, acc3, 0, 0, 0);
  }
  f32x4 accs[4] = {acc0, acc1, acc2, acc3};
#pragma unroll
  for (int i = 0; i < 4; i++) {
    int col = n0 + 16 * i + mr;
    float bv = bias[col];
#pragma unroll
    for (int rr2 = 0; rr2 < 4; rr2++) {
      int rr = m0 + 16 * w + quad * 4 + rr2;
      int lout = (rr >> 8) * XROWS + 3 + (rr & 255);
      xgb[(size_t)lout * 4096 + col] = accs[i][rr2] + bv;
    }
  }
}

// ---------------- K4: out_proj MFMA GEMM + bias + residual (fp32 out) ----------------
__global__ __launch_bounds__(256) void k_gemm2_mfma(const u16* __restrict__ A,   // yb [512][2048] bf16
                                                    const u16* __restrict__ W,   // wob [1024][2048] bf16
                                                    const float* __restrict__ bias,
                                                    const float* __restrict__ resid,
                                                    float* __restrict__ out, int l0) {
  __shared__ u16 Asm[64 * 40];
  __shared__ u16 Wsm[64 * 40];
  int t = threadIdx.x;
  int m0 = blockIdx.y * 64, n0 = blockIdx.x * 64;
  int srow = t >> 2, koff = (t & 3) * 8;
  const u16* Ag = A + (size_t)(m0 + srow) * DDIM + koff;
  const u16* Wg = W + (size_t)(n0 + srow) * DDIM + koff;
  int w = t >> 6, lane = t & 63;
  int quad = lane >> 4, mr = lane & 15;
  f32x4 z = {0.f, 0.f, 0.f, 0.f};
  f32x4 acc0 = z, acc1 = z, acc2 = z, acc3 = z;
  const u16* arp = &Asm[(16 * w + mr) * 40 + quad * 8];
  const u16* brp = &Wsm[mr * 40 + quad * 8];
  for (int k0 = 0; k0 < DDIM; k0 += 32) {
    uint4 av = *(const uint4*)(Ag + k0);
    uint4 wv = *(const uint4*)(Wg + k0);
    __syncthreads();
    *(uint4*)(&Asm[srow * 40 + koff]) = av;
    *(uint4*)(&Wsm[srow * 40 + koff]) = wv;
    __syncthreads();
    bf16x8 af = *(const bf16x8*)arp;
    bf16x8 b0 = *(const bf16x8*)(brp);
    bf16x8 b1 = *(const bf16x8*)(brp + 16 * 40);
    bf16x8 b2 = *(const bf16x8*)(brp + 32 * 40);
    bf16x8 b3 = *(const bf16x8*)(brp + 48 * 40);
    acc0 = __builtin_amdgcn_mfma_f32_16x16x32_bf16(af, b0, acc0, 0, 0, 0);
    acc1 = __builtin_amdgcn_mfma_f32_16x16x32_bf16(af, b1, acc1, 0, 0, 0);
    acc2 = __builtin_amdgcn_mfma_f32_16x16x32_bf16(af, b2, acc2, 0, 0, 0);
    acc3 = __builtin_amdgcn_mfma_f32_16x16x32_bf16(af, b3, acc3, 0, 0, 0);
  }
  f32x4 accs[4] = {acc0, acc1, acc2, acc3};
#pragma unroll
  for (int i = 0; i < 4; i++) {
    int col = n0 + 16 * i + mr;
    float bv = bias[col];
#pragma unroll
    for (int rr2 = 0; rr2 < 4; rr2++) {
      int rr = m0 + 16 * w + quad * 4 + rr2;
      int gout = ((rr >> 8) << 10) + l0 + (rr & 255);
      out[(size_t)gout * HDIM + col] =
          accs[i][rr2] + bv + resid[(size_t)gout * HDIM + col];
    }
  }
}

// ---------------- K2: conv+silu (in LDS) then x_proj (96 outs/token) ----------------
__global__ __launch_bounds__(256) void k_xprojc(const float* __restrict__ xgb,
                                                const float* __restrict__ cw,
                                                const float* __restrict__ cb,
                                                const float* __restrict__ w,
                                                const float* __restrict__ b,
                                                float* __restrict__ proj, int l0) {
  __shared__ float row[DDIM];
  int bb = blockIdx.x >> 8, lc = blockIdx.x & 255;
  int gl = l0 + lc;
  int t = threadIdx.x;
  int d = t * 8;
  float acc[8];
#pragma unroll
  for (int i = 0; i < 8; i++) acc[i] = cb[d + i];
  float cwv[8][4];
#pragma unroll
  for (int i = 0; i < 8; i++) {
    float4 v = *(const float4*)(cw + (d + i) * 4);
    cwv[i][0] = v.x; cwv[i][1] = v.y; cwv[i][2] = v.z; cwv[i][3] = v.w;
  }
#pragma unroll
  for (int j = 0; j < 4; j++) {
    if (gl - 3 + j >= 0) {  // causal guard; halo rows valid when this holds
      const float* xr = xgb + (size_t)(bb * XROWS + lc + j) * 4096 + d;
      float4 v0 = *(const float4*)xr;
      float4 v1 = *(const float4*)(xr + 4);
      acc[0] += v0.x * cwv[0][j]; acc[1] += v0.y * cwv[1][j];
      acc[2] += v0.z * cwv[2][j]; acc[3] += v0.w * cwv[3][j];
      acc[4] += v1.x * cwv[4][j]; acc[5] += v1.y * cwv[5][j];
      acc[6] += v1.z * cwv[6][j]; acc[7] += v1.w * cwv[7][j];
    }
  }
#pragma unroll
  for (int i = 0; i < 8; i++) row[d + i] = silu_f(acc[i]);
  __syncthreads();
  int wv = t >> 6, lane = t & 63;
  const float4* row4 = (const float4*)row;
  for (int o = wv; o < 96; o += 4) {
    const float4* wr4 = (const float4*)(w + (size_t)o * DDIM);
    float s0 = 0.f, s1 = 0.f, s2 = 0.f, s3 = 0.f;
#pragma unroll
    for (int k4 = 0; k4 < 8; k4++) {
      int idx = (k4 << 6) + lane;
      float4 wv4 = wr4[idx];
      float4 rv4 = row4[idx];
      s0 += rv4.x * wv4.x; s1 += rv4.y * wv4.y;
      s2 += rv4.z * wv4.z; s3 += rv4.w * wv4.w;
    }
    float s = (s0 + s1) + (s2 + s3);
    s += __shfl_xor(s, 32); s += __shfl_xor(s, 16);
    s += __shfl_xor(s, 8);  s += __shfl_xor(s, 4);
    s += __shfl_xor(s, 2);  s += __shfl_xor(s, 1);
    if (lane == 0) proj[(size_t)((bb << 10) + gl) * 96 + o] = s + b[o];
  }
}

// ---------------- K3: parallel selective scan (prefix-sum formulation) ----------------
__global__ __launch_bounds__(256) void k_scan(const float* __restrict__ proj,
                                              const float* __restrict__ xgb,
                                              const float* __restrict__ cw,
                                              const float* __restrict__ cb,
                                              const float* __restrict__ dtw,
                                              const float* __restrict__ dtb,
                                              const float* __restrict__ alog,
                                              const float* __restrict__ dparam,
                                              const float* __restrict__ cs,
                                              float* __restrict__ cumA,   // [4096] carried D
                                              float* __restrict__ SA,     // [65536] carried S per n
                                              u16* __restrict__ yb, int l0) {
  __shared__ float xs[XROWS];
  __shared__ float xcs[LC];
  __shared__ float ds[LC];
  __shared__ float Dl[LC];
  __shared__ float dtw_s[64];
  __shared__ float Bc[16][LC];
  __shared__ float Cc[16][LC];
  __shared__ float ys[4][LC];

  int t = threadIdx.x;
  int cidx = blockIdx.x;           // (b,d)
  int b = cidx >> 11;
  int d = cidx & (DDIM - 1);
  const float* pr = proj + ((size_t)(b << 10) + l0) * 96;

  xs[t] = (l0 == 0 && t < 3) ? 0.f : xgb[(size_t)(b * XROWS + t) * 4096 + d];
  if (t < 3) xs[LC + t] = xgb[(size_t)(b * XROWS + LC + t) * 4096 + d];
  if (t < 64) dtw_s[t] = dtw[(size_t)d * 64 + t];
  {
    const float4* bp = (const float4*)(pr + (size_t)t * 96 + 64);
    float4 b0 = bp[0], b1 = bp[1], b2 = bp[2], b3 = bp[3];
    float4 c0 = bp[4], c1 = bp[5], c2 = bp[6], c3 = bp[7];
    Bc[0][t] = b0.x; Bc[1][t] = b0.y; Bc[2][t] = b0.z; Bc[3][t] = b0.w;
    Bc[4][t] = b1.x; Bc[5][t] = b1.y; Bc[6][t] = b1.z; Bc[7][t] = b1.w;
    Bc[8][t] = b2.x; Bc[9][t] = b2.y; Bc[10][t] = b2.z; Bc[11][t] = b2.w;
    Bc[12][t] = b3.x; Bc[13][t] = b3.y; Bc[14][t] = b3.z; Bc[15][t] = b3.w;
    Cc[0][t] = c0.x; Cc[1][t] = c0.y; Cc[2][t] = c0.z; Cc[3][t] = c0.w;
    Cc[4][t] = c1.x; Cc[5][t] = c1.y; Cc[6][t] = c1.z; Cc[7][t] = c1.w;
    Cc[8][t] = c2.x; Cc[9][t] = c2.y; Cc[10][t] = c2.z; Cc[11][t] = c2.w;
    Cc[12][t] = c3.x; Cc[13][t] = c3.y; Cc[14][t] = c3.z; Cc[15][t] = c3.w;
  }
  __syncthreads();

  {
    float4 cwv = *(const float4*)(cw + d * 4);
    float v = cb[d] + cwv.w * xs[t + 3] + cwv.z * xs[t + 2] + cwv.y * xs[t + 1] + cwv.x * xs[t];
    xcs[t] = silu_f(v);
  }
  {
    float acc = dtb[d];
    const float4* pv = (const float4*)(pr + (size_t)t * 96);
#pragma unroll
    for (int k = 0; k < 16; k++) {
      float4 v = pv[k];
      acc += v.x * dtw_s[k * 4 + 0] + v.y * dtw_s[k * 4 + 1] +
             v.z * dtw_s[k * 4 + 2] + v.w * dtw_s[k * 4 + 3];
    }
    ds[t] = (acc > 20.f) ? acc : log1pf(__expf(acc));
  }
  __syncthreads();

  Dl[t] = ds[t];
  __syncthreads();
#pragma unroll
  for (int off = 1; off < LC; off <<= 1) {
    float v = (t >= off) ? Dl[t - off] : 0.f;
    __syncthreads();
    Dl[t] += v;
    __syncthreads();
  }

  int wv = t >> 6, lane = t & 63;
  float Dc = (l0 == 0) ? 0.f : cumA[cidx];
  float yacc0 = 0.f, yacc1 = 0.f, yacc2 = 0.f, yacc3 = 0.f;

  for (int r = 0; r < 4; r++) {
    int n = wv * 4 + r;
    float An = -__expf(alog[d * NST + n]);
    float state = cs[(size_t)(b * DDIM + d) * NST + n];
    int ci = (cidx << 4) | n;
    float Soff = (l0 == 0) ? 0.f : SA[ci];
#pragma unroll
    for (int s = 0; s < 4; s++) {
      int l = (s << 6) + lane;
      float dsl = ds[l];
      float De = (l == 0) ? 0.f : Dl[l - 1];
      float Di = Dl[l];
      float Pprev = __expf(An * (Dc + De));
      float P = __expf(An * (Dc + Di));
      float w = (dsl * Bc[n][l] * xcs[l]) / fmaxf(Pprev, 1e-10f);
#pragma unroll
      for (int off = 1; off < 64; off <<= 1) {
        float u = __shfl_up(w, off);
        if (lane >= off) w += u;
      }
      float S = Soff + w;
      float h = S * Pprev + state * P;
      float contrib = h * Cc[n][l];
      if (s == 0) yacc0 += contrib;
      else if (s == 1) yacc1 += contrib;
      else if (s == 2) yacc2 += contrib;
      else yacc3 += contrib;
      Soff = __shfl(S, 63);
    }
    if (lane == 0) SA[ci] = Soff;
  }
  ys[wv][lane] = yacc0;
  ys[wv][64 + lane] = yacc1;
  ys[wv][128 + lane] = yacc2;
  ys[wv][192 + lane] = yacc3;
  if (t == 0) cumA[cidx] = Dc + Dl[LC - 1];
  __syncthreads();

  {
    float y = ys[0][t] + ys[1][t] + ys[2][t] + ys[3][t] + xcs[t] * dparam[d];
    float g = xgb[(size_t)(b * XROWS + 3 + t) * 4096 + DDIM + d];
    yb[(size_t)((b << 8) + t) * DDIM + d] = f2bf(y * silu_f(g));
  }
}

extern "C" void kernel_launch(void* const* d_in, const int* in_sizes, int n_in,
                              void* d_out, int out_size, void* d_ws, size_t ws_size,
                              hipStream_t stream) {
  const float* inp    = (const float*)d_in[0];
  const float* cstate = (const float*)d_in[1];
  const float* norm_w = (const float*)d_in[2];
  const float* w1     = (const float*)d_in[3];
  const float* b1     = (const float*)d_in[4];
  const float* convw  = (const float*)d_in[5];
  const float* convb  = (const float*)d_in[6];
  const float* xpw    = (const float*)d_in[7];
  const float* xpb    = (const float*)d_in[8];
  const float* dtw    = (const float*)d_in[9];
  const float* dtb    = (const float*)d_in[10];
  const float* alog   = (const float*)d_in[11];
  const float* dparam = (const float*)d_in[12];
  const float* wo     = (const float*)d_in[13];
  const float* bo     = (const float*)d_in[14];
  float* out = (float*)d_out;

  // workspace layout, 28,426,240 B total
  char* wsb = (char*)d_ws;
  u16*   w1b  = (u16*)(wsb + 0);            //  8,388,608 B  [4096][1024] bf16
  u16*   wob  = (u16*)(wsb + 8388608);      //  4,194,304 B  [1024][2048] bf16
  u16*   xnb  = (u16*)(wsb + 12582912);     //  4,194,304 B  [2048][1024] bf16
  float* proj = (float*)(wsb + 16777216);   //    786,432 B  [2048][96]
  float* cumA = (float*)(wsb + 17563648);   //     16,384 B  [4096]
  float* SA   = (float*)(wsb + 17580032);   //    262,144 B  [65536]
  float* xgb  = (float*)(wsb + 17842176);   //  8,486,912 B  [2][259][4096] f32
  u16*   yb   = (u16*)(wsb + 26329088);     //  2,097,152 B  [2][256][2048] bf16

  k_castw<<<4096, 256, 0, stream>>>(w1, w1b);
  k_castw<<<2048, 256, 0, stream>>>(wo, wob);
  k_normcast<<<BL, 256, 0, stream>>>(inp, norm_w, xnb);
  for (int c = 0; c < 4; c++) {
    int l0 = c * LC;
    if (c > 0) k_halo<<<48, 256, 0, stream>>>(xgb);
    k_gemm1_mfma<<<dim3(64, 8), 256, 0, stream>>>(xnb, w1b, b1, xgb, l0);
    k_xprojc<<<2 * LC, 256, 0, stream>>>(xgb, convw, convb, xpw, xpb, proj, l0);
    k_scan<<<2 * DDIM, 256, 0, stream>>>(proj, xgb, convw, convb, dtw, dtb,
                                         alog, dparam, cstate, cumA, SA, yb, l0);
    k_gemm2_mfma<<<dim3(16, 8), 256, 0, stream>>>(yb, wob, bo, inp, out, l0);
  }
}

// Round 8
// 662.995 us; speedup vs baseline: 4.4753x; 1.0765x over previous
//
#include <hip/hip_runtime.h>
#include <stdint.h>

#define LSEQ 1024
#define HDIM 1024
#define DDIM 2048
#define BL 2048
#define NST 16
#define LC 256          // chunk length in tokens
#define XROWS (LC + 3)  // chunk rows + 3-row conv halo

typedef unsigned short u16;
typedef __attribute__((ext_vector_type(8))) short bf16x8;
typedef __attribute__((ext_vector_type(4))) float f32x4;

static __device__ __forceinline__ float silu_f(float v) { return v / (1.f + __expf(-v)); }
static __device__ __forceinline__ u16 f2bf(float f) {
  union { float f; unsigned int i; } c; c.f = f;
  unsigned int r = c.i + 0x7fffu + ((c.i >> 16) & 1u);
  return (u16)(r >> 16);
}

// ---------------- cast fp32 -> bf16 (weights, once per launch) ----------------
__global__ __launch_bounds__(256) void k_castw(const float* __restrict__ src,
                                               u16* __restrict__ dst) {
  int idx = blockIdx.x * 256 + threadIdx.x;
  float4 v = ((const float4*)src)[idx];
  ushort4 o;
  o.x = f2bf(v.x); o.y = f2bf(v.y); o.z = f2bf(v.z); o.w = f2bf(v.w);
  ((ushort4*)dst)[idx] = o;
}

// ---------------- rmsnorm + cast: xnb[row] = bf16(inp*scale*norm_w) ----------------
__global__ __launch_bounds__(256) void k_normcast(const float* __restrict__ inp,
                                                  const float* __restrict__ nw,
                                                  u16* __restrict__ xnb) {
  int row = blockIdx.x;
  int t = threadIdx.x;
  float4 xv = *(const float4*)(inp + (size_t)row * HDIM + t * 4);
  float ss = xv.x * xv.x + xv.y * xv.y + xv.z * xv.z + xv.w * xv.w;
  for (int off = 32; off > 0; off >>= 1) ss += __shfl_down(ss, off);
  __shared__ float red[4];
  if ((t & 63) == 0) red[t >> 6] = ss;
  __syncthreads();
  float tot = red[0] + red[1] + red[2] + red[3];
  float scale = rsqrtf(tot * (1.f / HDIM) + 1e-6f);
  float4 nv = *(const float4*)(nw + t * 4);
  ushort4 o;
  o.x = f2bf(xv.x * scale * nv.x); o.y = f2bf(xv.y * scale * nv.y);
  o.z = f2bf(xv.z * scale * nv.z); o.w = f2bf(xv.w * scale * nv.w);
  *(ushort4*)(xnb + (size_t)row * HDIM + t * 4) = o;
}

// ---------------- halo: copy last 3 x-rows of previous chunk to rows [0,3) ----------------
__global__ __launch_bounds__(256) void k_halo(float* __restrict__ xgb) {
  int idx = blockIdx.x * 256 + threadIdx.x;  // 2 batches * 3 rows * 2048 cols = 12288
  int b = idx / (3 * DDIM);
  int rem = idx - b * 3 * DDIM;
  int r = rem / DDIM;
  int c = rem - r * DDIM;
  xgb[(size_t)(b * XROWS + r) * 4096 + c] = xgb[(size_t)(b * XROWS + LC + r) * 4096 + c];
}

// ---------------- K1: in_proj MFMA GEMM: xg = xnb . w1b^T + b1 (fp32 out) ----------------
__global__ __launch_bounds__(256) void k_gemm1_mfma(const u16* __restrict__ A,   // [2048][1024] bf16
                                                    const u16* __restrict__ W,   // [4096][1024] bf16
                                                    const float* __restrict__ bias,
                                                    float* __restrict__ xgb, int l0) {
  __shared__ u16 Asm[64 * 40];
  __shared__ u16 Wsm[64 * 40];
  int t = threadIdx.x;
  int m0 = blockIdx.y * 64, n0 = blockIdx.x * 64;
  int srow = t >> 2, koff = (t & 3) * 8;
  int r = m0 + srow;
  int gin = ((r >> 8) << 10) + l0 + (r & 255);      // chunk row -> global BL row
  const u16* Ag = A + (size_t)gin * HDIM + koff;
  const u16* Wg = W + (size_t)(n0 + srow) * HDIM + koff;
  int w = t >> 6, lane = t & 63;
  int quad = lane >> 4, mr = lane & 15;
  f32x4 z = {0.f, 0.f, 0.f, 0.f};
  f32x4 acc0 = z, acc1 = z, acc2 = z, acc3 = z;
  const u16* arp = &Asm[(16 * w + mr) * 40 + quad * 8];
  const u16* brp = &Wsm[mr * 40 + quad * 8];
  for (int k0 = 0; k0 < HDIM; k0 += 32) {
    uint4 av = *(const uint4*)(Ag + k0);
    uint4 wv = *(const uint4*)(Wg + k0);
    __syncthreads();
    *(uint4*)(&Asm[srow * 40 + koff]) = av;
    *(uint4*)(&Wsm[srow * 40 + koff]) = wv;
    __syncthreads();
    bf16x8 af = *(const bf16x8*)arp;
    bf16x8 b0 = *(const bf16x8*)(brp);
    bf16x8 b1 = *(const bf16x8*)(brp + 16 * 40);
    bf16x8 b2 = *(const bf16x8*)(brp + 32 * 40);
    bf16x8 b3 = *(const bf16x8*)(brp + 48 * 40);
    acc0 = __builtin_amdgcn_mfma_f32_16x16x32_bf16(af, b0, acc0, 0, 0, 0);
    acc1 = __builtin_amdgcn_mfma_f32_16x16x32_bf16(af, b1, acc1, 0, 0, 0);
    acc2 = __builtin_amdgcn_mfma_f32_16x16x32_bf16(af, b2, acc2, 0, 0, 0);
    acc3 = __builtin_amdgcn_mfma_f32_16x16x32_bf16(af, b3, acc3, 0, 0, 0);
  }
  f32x4 accs[4] = {acc0, acc1, acc2, acc3};
#pragma unroll
  for (int i = 0; i < 4; i++) {
    int col = n0 + 16 * i + mr;
    float bv = bias[col];
#pragma unroll
    for (int rr2 = 0; rr2 < 4; rr2++) {
      int rr = m0 + 16 * w + quad * 4 + rr2;
      int lout = (rr >> 8) * XROWS + 3 + (rr & 255);
      xgb[(size_t)lout * 4096 + col] = accs[i][rr2] + bv;
    }
  }
}

// ---------------- K4: out_proj MFMA GEMM + bias + residual (fp32 out) ----------------
__global__ __launch_bounds__(256) void k_gemm2_mfma(const u16* __restrict__ A,   // yb [512][2048] bf16
                                                    const u16* __restrict__ W,   // wob [1024][2048] bf16
                                                    const float* __restrict__ bias,
                                                    const float* __restrict__ resid,
                                                    float* __restrict__ out, int l0) {
  __shared__ u16 Asm[64 * 40];
  __shared__ u16 Wsm[64 * 40];
  int t = threadIdx.x;
  int m0 = blockIdx.y * 64, n0 = blockIdx.x * 64;
  int srow = t >> 2, koff = (t & 3) * 8;
  const u16* Ag = A + (size_t)(m0 + srow) * DDIM + koff;
  const u16* Wg = W + (size_t)(n0 + srow) * DDIM + koff;
  int w = t >> 6, lane = t & 63;
  int quad = lane >> 4, mr = lane & 15;
  f32x4 z = {0.f, 0.f, 0.f, 0.f};
  f32x4 acc0 = z, acc1 = z, acc2 = z, acc3 = z;
  const u16* arp = &Asm[(16 * w + mr) * 40 + quad * 8];
  const u16* brp = &Wsm[mr * 40 + quad * 8];
  for (int k0 = 0; k0 < DDIM; k0 += 32) {
    uint4 av = *(const uint4*)(Ag + k0);
    uint4 wv = *(const uint4*)(Wg + k0);
    __syncthreads();
    *(uint4*)(&Asm[srow * 40 + koff]) = av;
    *(uint4*)(&Wsm[srow * 40 + koff]) = wv;
    __syncthreads();
    bf16x8 af = *(const bf16x8*)arp;
    bf16x8 b0 = *(const bf16x8*)(brp);
    bf16x8 b1 = *(const bf16x8*)(brp + 16 * 40);
    bf16x8 b2 = *(const bf16x8*)(brp + 32 * 40);
    bf16x8 b3 = *(const bf16x8*)(brp + 48 * 40);
    acc0 = __builtin_amdgcn_mfma_f32_16x16x32_bf16(af, b0, acc0, 0, 0, 0);
    acc1 = __builtin_amdgcn_mfma_f32_16x16x32_bf16(af, b1, acc1, 0, 0, 0);
    acc2 = __builtin_amdgcn_mfma_f32_16x16x32_bf16(af, b2, acc2, 0, 0, 0);
    acc3 = __builtin_amdgcn_mfma_f32_16x16x32_bf16(af, b3, acc3, 0, 0, 0);
  }
  f32x4 accs[4] = {acc0, acc1, acc2, acc3};
#pragma unroll
  for (int i = 0; i < 4; i++) {
    int col = n0 + 16 * i + mr;
    float bv = bias[col];
#pragma unroll
    for (int rr2 = 0; rr2 < 4; rr2++) {
      int rr = m0 + 16 * w + quad * 4 + rr2;
      int gout = ((rr >> 8) << 10) + l0 + (rr & 255);
      out[(size_t)gout * HDIM + col] =
          accs[i][rr2] + bv + resid[(size_t)gout * HDIM + col];
    }
  }
}

// ---------------- K2: conv+silu (in LDS) then x_proj (96 outs/token) ----------------
__global__ __launch_bounds__(256) void k_xprojc(const float* __restrict__ xgb,
                                                const float* __restrict__ cw,
                                                const float* __restrict__ cb,
                                                const float* __restrict__ w,
                                                const float* __restrict__ b,
                                                float* __restrict__ proj, int l0) {
  __shared__ float row[DDIM];
  int bb = blockIdx.x >> 8, lc = blockIdx.x & 255;
  int gl = l0 + lc;
  int t = threadIdx.x;
  int d = t * 8;
  float acc[8];
#pragma unroll
  for (int i = 0; i < 8; i++) acc[i] = cb[d + i];
  float cwv[8][4];
#pragma unroll
  for (int i = 0; i < 8; i++) {
    float4 v = *(const float4*)(cw + (d + i) * 4);
    cwv[i][0] = v.x; cwv[i][1] = v.y; cwv[i][2] = v.z; cwv[i][3] = v.w;
  }
#pragma unroll
  for (int j = 0; j < 4; j++) {
    if (gl - 3 + j >= 0) {  // causal guard; halo rows valid when this holds
      const float* xr = xgb + (size_t)(bb * XROWS + lc + j) * 4096 + d;
      float4 v0 = *(const float4*)xr;
      float4 v1 = *(const float4*)(xr + 4);
      acc[0] += v0.x * cwv[0][j]; acc[1] += v0.y * cwv[1][j];
      acc[2] += v0.z * cwv[2][j]; acc[3] += v0.w * cwv[3][j];
      acc[4] += v1.x * cwv[4][j]; acc[5] += v1.y * cwv[5][j];
      acc[6] += v1.z * cwv[6][j]; acc[7] += v1.w * cwv[7][j];
    }
  }
#pragma unroll
  for (int i = 0; i < 8; i++) row[d + i] = silu_f(acc[i]);
  __syncthreads();
  int wv = t >> 6, lane = t & 63;
  const float4* row4 = (const float4*)row;
  for (int o = wv; o < 96; o += 4) {
    const float4* wr4 = (const float4*)(w + (size_t)o * DDIM);
    float s0 = 0.f, s1 = 0.f, s2 = 0.f, s3 = 0.f;
#pragma unroll
    for (int k4 = 0; k4 < 8; k4++) {
      int idx = (k4 << 6) + lane;
      float4 wv4 = wr4[idx];
      float4 rv4 = row4[idx];
      s0 += rv4.x * wv4.x; s1 += rv4.y * wv4.y;
      s2 += rv4.z * wv4.z; s3 += rv4.w * wv4.w;
    }
    float s = (s0 + s1) + (s2 + s3);
    s += __shfl_xor(s, 32); s += __shfl_xor(s, 16);
    s += __shfl_xor(s, 8);  s += __shfl_xor(s, 4);
    s += __shfl_xor(s, 2);  s += __shfl_xor(s, 1);
    if (lane == 0) proj[(size_t)((bb << 10) + gl) * 96 + o] = s + b[o];
  }
}

// ---------------- K3: parallel selective scan, register B/C + wave-scan prefix ----------------
__global__ __launch_bounds__(256) void k_scan(const float* __restrict__ proj,
                                              const float* __restrict__ xgb,
                                              const float* __restrict__ cw,
                                              const float* __restrict__ cb,
                                              const float* __restrict__ dtw,
                                              const float* __restrict__ dtb,
                                              const float* __restrict__ alog,
                                              const float* __restrict__ dparam,
                                              const float* __restrict__ cs,
                                              float* __restrict__ cumA,   // [4096] carried D
                                              float* __restrict__ SA,     // [65536] carried S per n
                                              u16* __restrict__ yb, int l0) {
  __shared__ float xs[XROWS];
  __shared__ float xcs[LC];
  __shared__ float ds_s[LC];
  __shared__ float Dl[LC];
  __shared__ float dtw_s[64];
  __shared__ float wtot[4];
  __shared__ float ys[4][LC];

  int t = threadIdx.x;
  // XCD-aware swizzle: XCD x owns a contiguous 512-wide d range -> 64B lines of
  // the strided xgb column reads are fetched by exactly one XCD's L2.
  int cidx = ((blockIdx.x & 7) << 9) | (blockIdx.x >> 3);   // (b,d)
  int b = cidx >> 11;
  int d = cidx & (DDIM - 1);
  int wv = t >> 6, lane = t & 63;
  const float* pr = proj + ((size_t)(b << 10) + l0) * 96;

  // stage x column (with halo)
  xs[t] = (l0 == 0 && t < 3) ? 0.f : xgb[(size_t)(b * XROWS + t) * 4096 + d];
  if (t < 3) xs[LC + t] = xgb[(size_t)(b * XROWS + LC + t) * 4096 + d];
  if (t < 64) dtw_s[t] = dtw[(size_t)d * 64 + t];

  // per-thread B/C fragment preload (registers, L2-hot proj)
  float Bn[4][4], Cn[4][4];
#pragma unroll
  for (int r = 0; r < 4; r++) {
    int n = wv * 4 + r;
#pragma unroll
    for (int s = 0; s < 4; s++) {
      int l = (s << 6) + lane;
      Bn[r][s] = pr[(size_t)l * 96 + 64 + n];
      Cn[r][s] = pr[(size_t)l * 96 + 80 + n];
    }
  }
  float An[4], AnDc[4], state[4], Soff[4];
  float Dc = (l0 == 0) ? 0.f : cumA[cidx];
#pragma unroll
  for (int r = 0; r < 4; r++) {
    int n = wv * 4 + r;
    An[r] = -__expf(alog[d * NST + n]);
    AnDc[r] = An[r] * Dc;
    state[r] = cs[(size_t)(b * DDIM + d) * NST + n];
    Soff[r] = (l0 == 0) ? 0.f : SA[(cidx << 4) | n];
  }
  __syncthreads();

  // conv + silu (thread t -> token t)
  {
    float4 cwv = *(const float4*)(cw + d * 4);
    float v = cb[d] + cwv.w * xs[t + 3] + cwv.z * xs[t + 2] + cwv.y * xs[t + 1] + cwv.x * xs[t];
    xcs[t] = silu_f(v);
  }
  // delta (thread t -> token t): 64-dot + softplus
  float dval;
  {
    float acc = dtb[d];
    const float4* pv = (const float4*)(pr + (size_t)t * 96);
#pragma unroll
    for (int k = 0; k < 16; k++) {
      float4 v = pv[k];
      acc += v.x * dtw_s[k * 4 + 0] + v.y * dtw_s[k * 4 + 1] +
             v.z * dtw_s[k * 4 + 2] + v.w * dtw_s[k * 4 + 3];
    }
    dval = (acc > 20.f) ? acc : log1pf(__expf(acc));
    ds_s[t] = dval;
  }
  // prefix sum of delta: wave shfl scan + cross-wave offsets (2 syncs)
  {
    float val = dval;
#pragma unroll
    for (int off = 1; off < 64; off <<= 1) {
      float u = __shfl_up(val, off);
      if (lane >= off) val += u;
    }
    if (lane == 63) wtot[wv] = val;
    __syncthreads();
    float woff = 0.f;
#pragma unroll
    for (int i = 0; i < 3; i++) if (i < wv) woff += wtot[i];
    Dl[t] = val + woff;
    __syncthreads();
  }

  // main scan: s outer (sequential carry), r inner (independent n)
#pragma unroll
  for (int s = 0; s < 4; s++) {
    int l = (s << 6) + lane;
    float dsl = ds_s[l];
    float De = (l == 0) ? 0.f : Dl[l - 1];
    float Di = Dl[l];
    float xcl = xcs[l];
    float yl = 0.f;
#pragma unroll
    for (int r = 0; r < 4; r++) {
      float Pprev = __expf(AnDc[r] + An[r] * De);
      float P = __expf(AnDc[r] + An[r] * Di);
      float w = (dsl * Bn[r][s] * xcl) / fmaxf(Pprev, 1e-10f);
#pragma unroll
      for (int off = 1; off < 64; off <<= 1) {
        float u = __shfl_up(w, off);
        if (lane >= off) w += u;
      }
      float S = Soff[r] + w;
      float h = S * Pprev + state[r] * P;
      yl += h * Cn[r][s];
      Soff[r] = __shfl(S, 63);
    }
    ys[wv][l] = yl;
  }
  if (lane == 0) {
#pragma unroll
    for (int r = 0; r < 4; r++) SA[(cidx << 4) | (wv * 4 + r)] = Soff[r];
  }
  if (t == 0) cumA[cidx] = Dc + Dl[LC - 1];
  __syncthreads();

  // final: y = sum over waves + D-term, gate, write (bf16 for gemm2's A operand)
  {
    float y = ys[0][t] + ys[1][t] + ys[2][t] + ys[3][t] + xcs[t] * dparam[d];
    float g = xgb[(size_t)(b * XROWS + 3 + t) * 4096 + DDIM + d];
    yb[(size_t)((b << 8) + t) * DDIM + d] = f2bf(y * silu_f(g));
  }
}

extern "C" void kernel_launch(void* const* d_in, const int* in_sizes, int n_in,
                              void* d_out, int out_size, void* d_ws, size_t ws_size,
                              hipStream_t stream) {
  const float* inp    = (const float*)d_in[0];
  const float* cstate = (const float*)d_in[1];
  const float* norm_w = (const float*)d_in[2];
  const float* w1     = (const float*)d_in[3];
  const float* b1     = (const float*)d_in[4];
  const float* convw  = (const float*)d_in[5];
  const float* convb  = (const float*)d_in[6];
  const float* xpw    = (const float*)d_in[7];
  const float* xpb    = (const float*)d_in[8];
  const float* dtw    = (const float*)d_in[9];
  const float* dtb    = (const float*)d_in[10];
  const float* alog   = (const float*)d_in[11];
  const float* dparam = (const float*)d_in[12];
  const float* wo     = (const float*)d_in[13];
  const float* bo     = (const float*)d_in[14];
  float* out = (float*)d_out;

  // workspace layout, 28,426,240 B total
  char* wsb = (char*)d_ws;
  u16*   w1b  = (u16*)(wsb + 0);            //  8,388,608 B  [4096][1024] bf16
  u16*   wob  = (u16*)(wsb + 8388608);      //  4,194,304 B  [1024][2048] bf16
  u16*   xnb  = (u16*)(wsb + 12582912);     //  4,194,304 B  [2048][1024] bf16
  float* proj = (float*)(wsb + 16777216);   //    786,432 B  [2048][96]
  float* cumA = (float*)(wsb + 17563648);   //     16,384 B  [4096]
  float* SA   = (float*)(wsb + 17580032);   //    262,144 B  [65536]
  float* xgb  = (float*)(wsb + 17842176);   //  8,486,912 B  [2][259][4096] f32
  u16*   yb   = (u16*)(wsb + 26329088);     //  2,097,152 B  [2][256][2048] bf16

  k_castw<<<4096, 256, 0, stream>>>(w1, w1b);
  k_castw<<<2048, 256, 0, stream>>>(wo, wob);
  k_normcast<<<BL, 256, 0, stream>>>(inp, norm_w, xnb);
  for (int c = 0; c < 4; c++) {
    int l0 = c * LC;
    if (c > 0) k_halo<<<48, 256, 0, stream>>>(xgb);
    k_gemm1_mfma<<<dim3(64, 8), 256, 0, stream>>>(xnb, w1b, b1, xgb, l0);
    k_xprojc<<<2 * LC, 256, 0, stream>>>(xgb, convw, convb, xpw, xpb, proj, l0);
    k_scan<<<2 * DDIM, 256, 0, stream>>>(proj, xgb, convw, convb, dtw, dtb,
                                         alog, dparam, cstate, cumA, SA, yb, l0);
    k_gemm2_mfma<<<dim3(16, 8), 256, 0, stream>>>(yb, wob, bo, inp, out, l0);
  }
}